// Round 15
// baseline (303.622 us; speedup 1.0000x reference)
//
#include <hip/hip_runtime.h>
#include <cstdint>
#include <cstddef>

#define I_DIM 1024
#define O_DIM 1024
#define B_DIM 128
#define T_DIM 100
#define PANEL 32768  // fragment-tiled panel stride (ushorts) = 64q*64lane*8
#define QSTep 512    // per-q stride (ushorts) = 64 lanes * 8

typedef __attribute__((ext_vector_type(8))) __bf16 bf16x8;
typedef __attribute__((ext_vector_type(16))) float f32x16;

// Workgroup barrier that drains only LDS ops (lgkmcnt=0); global loads and
// stores stay in flight. simm16 = vm[3:0]=0xF | exp=7<<4 | lgkm=0<<8 |
// vm[5:4]=3<<14 = 0xC07F.
__device__ __forceinline__ void wg_barrier_lgkm() {
  __asm__ volatile("" ::: "memory");
  __builtin_amdgcn_s_waitcnt(0xC07F);
  __builtin_amdgcn_s_barrier();
  __asm__ volatile("" ::: "memory");
}

__device__ __forceinline__ unsigned short bf16rn(float x) {
  unsigned u = __float_as_uint(x);
  unsigned r = u + 0x7FFFu + ((u >> 16) & 1u);
  return (unsigned short)(r >> 16);
}
__device__ __forceinline__ void split2(float x, unsigned short& h,
                                       unsigned short& l) {
  h = bf16rn(x);
  float hf = __uint_as_float(((unsigned)h) << 16);
  l = bf16rn(x - hf);
}

// ---------------------------------------------------------------------------
// prep: fused split_wT (WGs 0..255) + xsplit (WGs 256..655).
// ---------------------------------------------------------------------------
__global__ __launch_bounds__(256) void prep_kernel(
    const float* __restrict__ w, const float* __restrict__ x,
    unsigned short* __restrict__ wTth, unsigned short* __restrict__ wTtl,
    unsigned short* __restrict__ xth, unsigned short* __restrict__ xtl,
    double* __restrict__ normpart) {
  __shared__ float tile[64][65];
  __shared__ double red[4][64];
  const int id = blockIdx.x;
  const int tid = threadIdx.x;
  if (id < 256) {  // ---- split_wT ----
    const int a0 = (id >> 4) * 64, o0 = (id & 15) * 64;
    const int tr = tid >> 4, tc4 = (tid & 15) * 4;
#pragma unroll
    for (int rr = 0; rr < 64; rr += 16) {
      float4 v = *(const float4*)&w[(size_t)(a0 + tr + rr) * O_DIM + o0 + tc4];
      tile[tr + rr][tc4 + 0] = v.x;
      tile[tr + rr][tc4 + 1] = v.y;
      tile[tr + rr][tc4 + 2] = v.z;
      tile[tr + rr][tc4 + 3] = v.w;
    }
    __syncthreads();
    {
      const int ol = tid & 63, seg = tid >> 6;
      double s = 0.0;
#pragma unroll
      for (int i = 0; i < 16; ++i) {
        double v = (double)tile[seg * 16 + i][ol];
        s += v * v;
      }
      red[seg][ol] = s;
    }
    const int q = (a0 >> 4) + (tc4 >> 4);
    const int kh = (tc4 >> 3) & 1;
    const int inner = tc4 & 7;
#pragma unroll
    for (int rr = 0; rr < 64; rr += 16) {
      int o = o0 + tr + rr;
      unsigned short hh[4], ll[4];
#pragma unroll
      for (int j = 0; j < 4; ++j) split2(tile[tc4 + j][tr + rr], hh[j], ll[j]);
      int l = (o & 31) + 32 * kh;
      size_t base = ((size_t)(o >> 5) * PANEL) + (size_t)q * QSTep +
                    (size_t)l * 8 + inner;
      *(ushort4*)&wTth[base] = make_ushort4(hh[0], hh[1], hh[2], hh[3]);
      *(ushort4*)&wTtl[base] = make_ushort4(ll[0], ll[1], ll[2], ll[3]);
    }
    __syncthreads();
    if (tid < 64)
      normpart[(size_t)(a0 >> 6) * O_DIM + o0 + tid] =
          red[0][tid] + red[1][tid] + red[2][tid] + red[3][tid];
  } else {  // ---- xsplit ----
    const int p = id - 256;
    const int wq = tid >> 6, lane = tid & 63;
    const int row = lane & 31, kh = lane >> 5;
    const float* src = x + (size_t)(p * 32 + row) * I_DIM + kh * 8;
#pragma unroll 4
    for (int i = 0; i < 16; ++i) {
      const int q = i * 4 + wq;
      const float* s = src + q * 16;
      float4 v0 = *(const float4*)(s);
      float4 v1 = *(const float4*)(s + 4);
      unsigned short h[8], l[8];
      split2(v0.x, h[0], l[0]);
      split2(v0.y, h[1], l[1]);
      split2(v0.z, h[2], l[2]);
      split2(v0.w, h[3], l[3]);
      split2(v1.x, h[4], l[4]);
      split2(v1.y, h[5], l[5]);
      split2(v1.z, h[6], l[6]);
      split2(v1.w, h[7], l[7]);
      size_t base = ((size_t)p * PANEL) + (size_t)q * QSTep + (size_t)lane * 8;
      *(ushort4*)&xth[base] = make_ushort4(h[0], h[1], h[2], h[3]);
      *(ushort4*)&xth[base + 4] = make_ushort4(h[4], h[5], h[6], h[7]);
      *(ushort4*)&xtl[base] = make_ushort4(l[0], l[1], l[2], l[3]);
      *(ushort4*)&xtl[base + 4] = make_ushort4(l[4], l[5], l[6], l[7]);
    }
  }
}

// ---------------------------------------------------------------------------
// gemm_fused: EXACT R1 form (validated: gemm 129 us, FETCH 85 MB, absmax 0).
// Zero-LDS streaming structure is L2-BW/latency bounded at ~129 us.
// ---------------------------------------------------------------------------
__global__ __launch_bounds__(256) void gemm_fused(
    const unsigned short* __restrict__ xth,
    const unsigned short* __restrict__ xtl,
    const unsigned short* __restrict__ wTth,
    const unsigned short* __restrict__ wTtl, const float* __restrict__ v,
    const float* __restrict__ beta_p, float* __restrict__ h,
    float* __restrict__ M) {
  const int tid = threadIdx.x;
  const int wv = tid >> 6, lane = tid & 63;
  const int lm = lane & 31, lkh = lane >> 5;
  if (blockIdx.y < 100) {  // ---------------- hgemm ----------------
    const int lin = blockIdx.y * 16 + blockIdx.x;  // [0,1600)
    const int slin = (lin & 7) * 200 + (lin >> 3);
    const int row0 = (slin >> 4) * 128, col0 = (slin & 15) * 64;
    const int wm = wv >> 1, wn = wv & 1;
    f32x16 acc[2];
#pragma unroll
    for (int a = 0; a < 2; ++a)
#pragma unroll
      for (int e = 0; e < 16; ++e) acc[a][e] = 0.f;
    const unsigned short *pah[2], *pal[2], *pbh, *pbl;
#pragma unroll
    for (int mt = 0; mt < 2; ++mt) {
      size_t offA =
          ((size_t)((row0 >> 5) + wm * 2 + mt) * PANEL) + (size_t)lane * 8;
      pah[mt] = xth + offA;
      pal[mt] = xtl + offA;
    }
    {
      size_t offB = ((size_t)((col0 >> 5) + wn) * PANEL) + (size_t)lane * 8;
      pbh = wTth + offB;
      pbl = wTtl + offB;
    }
    bf16x8 fah[2][2], fal[2][2], fbh[2], fbl[2];  // [buf][tile] / [buf]
#pragma unroll
    for (int mt = 0; mt < 2; ++mt) {
      fah[0][mt] = *(const bf16x8*)(pah[mt]);
      fal[0][mt] = *(const bf16x8*)(pal[mt]);
    }
    fbh[0] = *(const bf16x8*)(pbh);
    fbl[0] = *(const bf16x8*)(pbl);
#pragma unroll 2
    for (int q = 0; q < 64; ++q) {
      const int cb = q & 1;
      if (q < 63) {
        size_t d = (size_t)(q + 1) * QSTep;
#pragma unroll
        for (int mt = 0; mt < 2; ++mt) {
          fah[cb ^ 1][mt] = *(const bf16x8*)(pah[mt] + d);
          fal[cb ^ 1][mt] = *(const bf16x8*)(pal[mt] + d);
        }
        fbh[cb ^ 1] = *(const bf16x8*)(pbh + d);
        fbl[cb ^ 1] = *(const bf16x8*)(pbl + d);
      }
#pragma unroll
      for (int mt = 0; mt < 2; ++mt)
        acc[mt] = __builtin_amdgcn_mfma_f32_32x32x16_bf16(fah[cb][mt], fbh[cb],
                                                          acc[mt], 0, 0, 0);
#pragma unroll
      for (int mt = 0; mt < 2; ++mt)
        acc[mt] = __builtin_amdgcn_mfma_f32_32x32x16_bf16(fah[cb][mt], fbl[cb],
                                                          acc[mt], 0, 0, 0);
#pragma unroll
      for (int mt = 0; mt < 2; ++mt)
        acc[mt] = __builtin_amdgcn_mfma_f32_32x32x16_bf16(fal[cb][mt], fbh[cb],
                                                          acc[mt], 0, 0, 0);
    }
    const int col = col0 + wn * 32 + lm;
#pragma unroll
    for (int mt = 0; mt < 2; ++mt)
#pragma unroll
      for (int r = 0; r < 16; ++r) {
        int row = row0 + wm * 64 + mt * 32 + (r & 3) + 8 * (r >> 2) + 4 * lkh;
        h[(size_t)row * O_DIM + col] = acc[mt][r];
      }
  } else {  // ---------------- mbuild ----------------
    const int i0 = (blockIdx.y - 100) * 64, o0 = blockIdx.x * 64;
    const int wm = wv >> 1, wn = wv & 1;
    f32x16 acc;
#pragma unroll
    for (int e = 0; e < 16; ++e) acc[e] = 0.f;
    const size_t offA = ((size_t)((i0 >> 5) + wm) * PANEL) + (size_t)lane * 8;
    const size_t offB = ((size_t)((o0 >> 5) + wn) * PANEL) + (size_t)lane * 8;
    bf16x8 ah[2], al[2], bh[2], bl[2];
    ah[0] = *(const bf16x8*)(wTth + offA);
    al[0] = *(const bf16x8*)(wTtl + offA);
    bh[0] = *(const bf16x8*)(wTth + offB);
    bl[0] = *(const bf16x8*)(wTtl + offB);
#pragma unroll 2
    for (int q = 0; q < 64; ++q) {
      const int cb = q & 1;
      if (q < 63) {
        size_t d = (size_t)(q + 1) * QSTep;
        ah[cb ^ 1] = *(const bf16x8*)(wTth + offA + d);
        al[cb ^ 1] = *(const bf16x8*)(wTtl + offA + d);
        bh[cb ^ 1] = *(const bf16x8*)(wTth + offB + d);
        bl[cb ^ 1] = *(const bf16x8*)(wTtl + offB + d);
      }
      acc =
          __builtin_amdgcn_mfma_f32_32x32x16_bf16(ah[cb], bh[cb], acc, 0, 0, 0);
      acc =
          __builtin_amdgcn_mfma_f32_32x32x16_bf16(ah[cb], bl[cb], acc, 0, 0, 0);
      acc =
          __builtin_amdgcn_mfma_f32_32x32x16_bf16(al[cb], bh[cb], acc, 0, 0, 0);
    }
    const float beta = beta_p[0];
    const float ombeta = 1.0f - beta;
    const int col = o0 + wn * 32 + lm;
#pragma unroll
    for (int r = 0; r < 16; ++r) {
      int row = i0 + wm * 32 + (r & 3) + 8 * (r >> 2) + 4 * lkh;
      M[(size_t)row * O_DIM + col] =
          ombeta * v[(size_t)row * O_DIM + col] - beta * acc[r];
    }
  }
}

// ---------------------------------------------------------------------------
// Scan R14: gather n-loop 4-way unrolled with 4 independent partial sums per
// neuron (l0..l3). The serial double-add dependency chain drops from ks to
// ks/4 (this was the scan's critical path -- R8's load-halving barely moved
// it because chain LENGTH is ks regardless of j-count). Loads for 4 spike
// rows issue independently; per-element loop overhead ~4x lower. Summation
// set identical, only re-associated (R8's 8-list reorder already proved
// double-sum reorder keeps absmax 0). Rest identical to validated R14.
// ---------------------------------------------------------------------------
__global__ __launch_bounds__(512) void scan_kernel(
    const float* __restrict__ h, const float* __restrict__ M,
    const double* __restrict__ normpart, const float* __restrict__ bvec,
    const float* __restrict__ beta_p, float* __restrict__ out,
    int* __restrict__ wgcnt) {
  __shared__ unsigned short wlist[2][8][128];
  __shared__ int wcnt[2][8];
  const int b = blockIdx.x, tid = threadIdx.x;
  const int wv = tid >> 6;  // 0..7
  const double beta = (double)beta_p[0];
  const double ombeta = 1.0 - beta;
  double mem[2] = {0.0, 0.0};
  double inv[2], bth[2];
  int o[2];
#pragma unroll
  for (int j = 0; j < 2; ++j) {
    o[j] = tid + j * 512;
    double s = 0.0;
#pragma unroll
    for (int g = 0; g < 16; ++g) s += normpart[(size_t)g * O_DIM + o[j]];
    inv[j] = 1.0 / (s + 1e-8);
    bth[j] = (double)bvec[o[j]];
  }
  if (tid < 16) wcnt[tid >> 3][tid & 7] = 0;
  __syncthreads();
  const float* hb = h + (size_t)b * T_DIM * O_DIM;
  float* ob = out + (size_t)b * T_DIM * O_DIM;
  float hv0[2], hv1[2];
#pragma unroll
  for (int j = 0; j < 2; ++j) {
    hv0[j] = hb[o[j]];
    hv1[j] = hb[O_DIM + o[j]];
  }
  for (int t = 0; t < T_DIM; ++t) {
    const int p = t & 1, np = p ^ 1;
    float hv2[2] = {0.f, 0.f};
    if (t + 2 < T_DIM) {
#pragma unroll
      for (int j = 0; j < 2; ++j) hv2[j] = hb[(size_t)(t + 2) * O_DIM + o[j]];
    }
    double l0[2] = {0.0, 0.0}, l1[2] = {0.0, 0.0};
    double l2[2] = {0.0, 0.0}, l3[2] = {0.0, 0.0};
    int ks = 0;
#pragma unroll
    for (int w = 0; w < 8; ++w) ks += wcnt[p][w];
    if (ks) {
#pragma unroll
      for (int w = 0; w < 8; ++w) {
        const int kw = wcnt[p][w];
        const unsigned short* wl = wlist[p][w];
        int n = 0;
        for (; n + 4 <= kw; n += 4) {
          const float* M0 = M + (size_t)wl[n] * O_DIM;
          const float* M1 = M + (size_t)wl[n + 1] * O_DIM;
          const float* M2 = M + (size_t)wl[n + 2] * O_DIM;
          const float* M3 = M + (size_t)wl[n + 3] * O_DIM;
#pragma unroll
          for (int j = 0; j < 2; ++j) {
            l0[j] += (double)M0[o[j]];
            l1[j] += (double)M1[o[j]];
            l2[j] += (double)M2[o[j]];
            l3[j] += (double)M3[o[j]];
          }
        }
        for (; n < kw; ++n) {
          const float* Mr = M + (size_t)wl[n] * O_DIM;
#pragma unroll
          for (int j = 0; j < 2; ++j) l0[j] += (double)Mr[o[j]];
        }
      }
    }
    unsigned cur = 0;
#pragma unroll
    for (int j = 0; j < 2; ++j) {
      double lat = (l0[j] + l1[j]) + (l2[j] + l3[j]);
      mem[j] = mem[j] * beta + (double)hv0[j] * ombeta + lat;
      double mthr = mem[j] * inv[j] - bth[j];
      bool s = mthr > 0.0;
      ob[(size_t)t * O_DIM + o[j]] = s ? 1.0f : 0.0f;
      unsigned long long mask = __ballot(s);
      if (s) {
        unsigned below = __builtin_amdgcn_mbcnt_lo((unsigned)mask, 0);
        below = __builtin_amdgcn_mbcnt_hi((unsigned)(mask >> 32), below);
        wlist[np][wv][cur + below] = (unsigned short)o[j];
      }
      cur += (unsigned)__popcll(mask);
      hv0[j] = hv1[j];
      hv1[j] = hv2[j];
    }
    if ((tid & 63) == 0) wcnt[np][wv] = (int)cur;
    wg_barrier_lgkm();
    if (tid == 0)
      wgcnt[b * T_DIM + t] = wcnt[np][0] + wcnt[np][1] + wcnt[np][2] +
                             wcnt[np][3] + wcnt[np][4] + wcnt[np][5] +
                             wcnt[np][6] + wcnt[np][7];
  }
}

// ---------------------------------------------------------------------------
// finalize: counts[t] = sum_b wgcnt[b][t]; loss & spread from exact ints.
// ---------------------------------------------------------------------------
__global__ void finalize_kernel(const int* __restrict__ wgcnt,
                                float* __restrict__ out) {
  __shared__ int sums[128];
  const int t = threadIdx.x;  // 128 threads
  int s = 0;
  if (t < T_DIM) {
    for (int b = 0; b < B_DIM; ++b) s += wgcnt[b * T_DIM + t];
  }
  sums[t] = s;
  __syncthreads();
  if (t == 0) {
    long long total = 0;
    int mx = 0;
    for (int i = 0; i < T_DIM; ++i) {
      total += sums[i];
      if (sums[i] > mx) mx = sums[i];
    }
    const double N = (double)B_DIM * T_DIM * O_DIM;
    out[(size_t)B_DIM * T_DIM * O_DIM] = (float)(0.5 * (double)total / N);
    out[(size_t)B_DIM * T_DIM * O_DIM + 1] =
        (float)((double)mx / (double)(B_DIM * O_DIM));
  }
}

extern "C" void kernel_launch(void* const* d_in, const int* in_sizes, int n_in,
                              void* d_out, int out_size, void* d_ws,
                              size_t ws_size, hipStream_t stream) {
  const float* x = (const float*)d_in[0];
  const float* w = (const float*)d_in[1];
  const float* v = (const float*)d_in[2];
  const float* beta = (const float*)d_in[3];
  const float* b = (const float*)d_in[4];
  float* out = (float*)d_out;

  char* ws = (char*)d_ws;
  const size_t OFF_M = 0;           // 4 MB
  const size_t OFF_H = 4194304;     // 50 MB
  const size_t OFF_WTH = 56623104;  // 2 MB
  const size_t OFF_WTL = 58720256;  // 2 MB
  const size_t OFF_NP = 60817408;   // 128 KB
  const size_t OFF_XTH = 60948992;  // 25 MB
  const size_t OFF_XTL = 87163392;  // 25 MB -> end 113377792 (proven fits)
  float* M = (float*)(ws + OFF_M);
  float* h = (float*)(ws + OFF_H);
  unsigned short* wTth = (unsigned short*)(ws + OFF_WTH);
  unsigned short* wTtl = (unsigned short*)(ws + OFF_WTL);
  double* normpart = (double*)(ws + OFF_NP);
  unsigned short* xth = (unsigned short*)(ws + OFF_XTH);
  unsigned short* xtl = (unsigned short*)(ws + OFF_XTL);
  // wgcnt reuses the (dead-by-then) xth region: gemm finished before scan.
  int* wgcnt = (int*)(ws + OFF_XTH);

  hipLaunchKernelGGL(prep_kernel, dim3(656), dim3(256), 0, stream, w, x, wTth,
                     wTtl, xth, xtl, normpart);
  hipLaunchKernelGGL(gemm_fused, dim3(16, 116), dim3(256), 0, stream, xth, xtl,
                     wTth, wTtl, v, beta, h, M);
  hipLaunchKernelGGL(scan_kernel, dim3(128), dim3(512), 0, stream, h, M,
                     normpart, b, beta, out, wgcnt);
  hipLaunchKernelGGL(finalize_kernel, dim3(1), dim3(128), 0, stream, wgcnt,
                     out);
}

// Round 18
// 299.971 us; speedup vs baseline: 1.0122x; 1.0122x over previous
//
#include <hip/hip_runtime.h>
#include <cstdint>
#include <cstddef>

#define I_DIM 1024
#define O_DIM 1024
#define B_DIM 128
#define T_DIM 100
#define PANEL 32768  // fragment-tiled panel stride (ushorts) = 64q*64lane*8
#define QSTep 512    // per-q stride (ushorts) = 64 lanes * 8

typedef __attribute__((ext_vector_type(8))) __bf16 bf16x8;
typedef __attribute__((ext_vector_type(16))) float f32x16;

// Workgroup barrier that drains only LDS ops (lgkmcnt=0); global loads and
// stores stay in flight. simm16 = vm[3:0]=0xF | exp=7<<4 | lgkm=0<<8 |
// vm[5:4]=3<<14 = 0xC07F.
__device__ __forceinline__ void wg_barrier_lgkm() {
  __asm__ volatile("" ::: "memory");
  __builtin_amdgcn_s_waitcnt(0xC07F);
  __builtin_amdgcn_s_barrier();
  __asm__ volatile("" ::: "memory");
}

__device__ __forceinline__ unsigned short bf16rn(float x) {
  unsigned u = __float_as_uint(x);
  unsigned r = u + 0x7FFFu + ((u >> 16) & 1u);
  return (unsigned short)(r >> 16);
}
__device__ __forceinline__ void split2(float x, unsigned short& h,
                                       unsigned short& l) {
  h = bf16rn(x);
  float hf = __uint_as_float(((unsigned)h) << 16);
  l = bf16rn(x - hf);
}

// ---------------------------------------------------------------------------
// prep: fused split_wT (WGs 0..255) + xsplit (WGs 256..655).
// ---------------------------------------------------------------------------
__global__ __launch_bounds__(256) void prep_kernel(
    const float* __restrict__ w, const float* __restrict__ x,
    unsigned short* __restrict__ wTth, unsigned short* __restrict__ wTtl,
    unsigned short* __restrict__ xth, unsigned short* __restrict__ xtl,
    double* __restrict__ normpart) {
  __shared__ float tile[64][65];
  __shared__ double red[4][64];
  const int id = blockIdx.x;
  const int tid = threadIdx.x;
  if (id < 256) {  // ---- split_wT ----
    const int a0 = (id >> 4) * 64, o0 = (id & 15) * 64;
    const int tr = tid >> 4, tc4 = (tid & 15) * 4;
#pragma unroll
    for (int rr = 0; rr < 64; rr += 16) {
      float4 v = *(const float4*)&w[(size_t)(a0 + tr + rr) * O_DIM + o0 + tc4];
      tile[tr + rr][tc4 + 0] = v.x;
      tile[tr + rr][tc4 + 1] = v.y;
      tile[tr + rr][tc4 + 2] = v.z;
      tile[tr + rr][tc4 + 3] = v.w;
    }
    __syncthreads();
    {
      const int ol = tid & 63, seg = tid >> 6;
      double s = 0.0;
#pragma unroll
      for (int i = 0; i < 16; ++i) {
        double v = (double)tile[seg * 16 + i][ol];
        s += v * v;
      }
      red[seg][ol] = s;
    }
    const int q = (a0 >> 4) + (tc4 >> 4);
    const int kh = (tc4 >> 3) & 1;
    const int inner = tc4 & 7;
#pragma unroll
    for (int rr = 0; rr < 64; rr += 16) {
      int o = o0 + tr + rr;
      unsigned short hh[4], ll[4];
#pragma unroll
      for (int j = 0; j < 4; ++j) split2(tile[tc4 + j][tr + rr], hh[j], ll[j]);
      int l = (o & 31) + 32 * kh;
      size_t base = ((size_t)(o >> 5) * PANEL) + (size_t)q * QSTep +
                    (size_t)l * 8 + inner;
      *(ushort4*)&wTth[base] = make_ushort4(hh[0], hh[1], hh[2], hh[3]);
      *(ushort4*)&wTtl[base] = make_ushort4(ll[0], ll[1], ll[2], ll[3]);
    }
    __syncthreads();
    if (tid < 64)
      normpart[(size_t)(a0 >> 6) * O_DIM + o0 + tid] =
          red[0][tid] + red[1][tid] + red[2][tid] + red[3][tid];
  } else {  // ---- xsplit ----
    const int p = id - 256;
    const int wq = tid >> 6, lane = tid & 63;
    const int row = lane & 31, kh = lane >> 5;
    const float* src = x + (size_t)(p * 32 + row) * I_DIM + kh * 8;
#pragma unroll 4
    for (int i = 0; i < 16; ++i) {
      const int q = i * 4 + wq;
      const float* s = src + q * 16;
      float4 v0 = *(const float4*)(s);
      float4 v1 = *(const float4*)(s + 4);
      unsigned short h[8], l[8];
      split2(v0.x, h[0], l[0]);
      split2(v0.y, h[1], l[1]);
      split2(v0.z, h[2], l[2]);
      split2(v0.w, h[3], l[3]);
      split2(v1.x, h[4], l[4]);
      split2(v1.y, h[5], l[5]);
      split2(v1.z, h[6], l[6]);
      split2(v1.w, h[7], l[7]);
      size_t base = ((size_t)p * PANEL) + (size_t)q * QSTep + (size_t)lane * 8;
      *(ushort4*)&xth[base] = make_ushort4(h[0], h[1], h[2], h[3]);
      *(ushort4*)&xth[base + 4] = make_ushort4(h[4], h[5], h[6], h[7]);
      *(ushort4*)&xtl[base] = make_ushort4(l[0], l[1], l[2], l[3]);
      *(ushort4*)&xtl[base + 4] = make_ushort4(l[4], l[5], l[6], l[7]);
    }
  }
}

// ---------------------------------------------------------------------------
// gemm_fused: EXACT R1 form (validated: gemm 129 us, FETCH 85 MB, absmax 0).
// Zero-LDS streaming structure is L2-BW/latency bounded at ~129 us.
// ---------------------------------------------------------------------------
__global__ __launch_bounds__(256) void gemm_fused(
    const unsigned short* __restrict__ xth,
    const unsigned short* __restrict__ xtl,
    const unsigned short* __restrict__ wTth,
    const unsigned short* __restrict__ wTtl, const float* __restrict__ v,
    const float* __restrict__ beta_p, float* __restrict__ h,
    float* __restrict__ M) {
  const int tid = threadIdx.x;
  const int wv = tid >> 6, lane = tid & 63;
  const int lm = lane & 31, lkh = lane >> 5;
  if (blockIdx.y < 100) {  // ---------------- hgemm ----------------
    const int lin = blockIdx.y * 16 + blockIdx.x;  // [0,1600)
    const int slin = (lin & 7) * 200 + (lin >> 3);
    const int row0 = (slin >> 4) * 128, col0 = (slin & 15) * 64;
    const int wm = wv >> 1, wn = wv & 1;
    f32x16 acc[2];
#pragma unroll
    for (int a = 0; a < 2; ++a)
#pragma unroll
      for (int e = 0; e < 16; ++e) acc[a][e] = 0.f;
    const unsigned short *pah[2], *pal[2], *pbh, *pbl;
#pragma unroll
    for (int mt = 0; mt < 2; ++mt) {
      size_t offA =
          ((size_t)((row0 >> 5) + wm * 2 + mt) * PANEL) + (size_t)lane * 8;
      pah[mt] = xth + offA;
      pal[mt] = xtl + offA;
    }
    {
      size_t offB = ((size_t)((col0 >> 5) + wn) * PANEL) + (size_t)lane * 8;
      pbh = wTth + offB;
      pbl = wTtl + offB;
    }
    bf16x8 fah[2][2], fal[2][2], fbh[2], fbl[2];  // [buf][tile] / [buf]
#pragma unroll
    for (int mt = 0; mt < 2; ++mt) {
      fah[0][mt] = *(const bf16x8*)(pah[mt]);
      fal[0][mt] = *(const bf16x8*)(pal[mt]);
    }
    fbh[0] = *(const bf16x8*)(pbh);
    fbl[0] = *(const bf16x8*)(pbl);
#pragma unroll 2
    for (int q = 0; q < 64; ++q) {
      const int cb = q & 1;
      if (q < 63) {
        size_t d = (size_t)(q + 1) * QSTep;
#pragma unroll
        for (int mt = 0; mt < 2; ++mt) {
          fah[cb ^ 1][mt] = *(const bf16x8*)(pah[mt] + d);
          fal[cb ^ 1][mt] = *(const bf16x8*)(pal[mt] + d);
        }
        fbh[cb ^ 1] = *(const bf16x8*)(pbh + d);
        fbl[cb ^ 1] = *(const bf16x8*)(pbl + d);
      }
#pragma unroll
      for (int mt = 0; mt < 2; ++mt)
        acc[mt] = __builtin_amdgcn_mfma_f32_32x32x16_bf16(fah[cb][mt], fbh[cb],
                                                          acc[mt], 0, 0, 0);
#pragma unroll
      for (int mt = 0; mt < 2; ++mt)
        acc[mt] = __builtin_amdgcn_mfma_f32_32x32x16_bf16(fah[cb][mt], fbl[cb],
                                                          acc[mt], 0, 0, 0);
#pragma unroll
      for (int mt = 0; mt < 2; ++mt)
        acc[mt] = __builtin_amdgcn_mfma_f32_32x32x16_bf16(fal[cb][mt], fbh[cb],
                                                          acc[mt], 0, 0, 0);
    }
    const int col = col0 + wn * 32 + lm;
#pragma unroll
    for (int mt = 0; mt < 2; ++mt)
#pragma unroll
      for (int r = 0; r < 16; ++r) {
        int row = row0 + wm * 64 + mt * 32 + (r & 3) + 8 * (r >> 2) + 4 * lkh;
        h[(size_t)row * O_DIM + col] = acc[mt][r];
      }
  } else {  // ---------------- mbuild ----------------
    const int i0 = (blockIdx.y - 100) * 64, o0 = blockIdx.x * 64;
    const int wm = wv >> 1, wn = wv & 1;
    f32x16 acc;
#pragma unroll
    for (int e = 0; e < 16; ++e) acc[e] = 0.f;
    const size_t offA = ((size_t)((i0 >> 5) + wm) * PANEL) + (size_t)lane * 8;
    const size_t offB = ((size_t)((o0 >> 5) + wn) * PANEL) + (size_t)lane * 8;
    bf16x8 ah[2], al[2], bh[2], bl[2];
    ah[0] = *(const bf16x8*)(wTth + offA);
    al[0] = *(const bf16x8*)(wTtl + offA);
    bh[0] = *(const bf16x8*)(wTth + offB);
    bl[0] = *(const bf16x8*)(wTtl + offB);
#pragma unroll 2
    for (int q = 0; q < 64; ++q) {
      const int cb = q & 1;
      if (q < 63) {
        size_t d = (size_t)(q + 1) * QSTep;
        ah[cb ^ 1] = *(const bf16x8*)(wTth + offA + d);
        al[cb ^ 1] = *(const bf16x8*)(wTtl + offA + d);
        bh[cb ^ 1] = *(const bf16x8*)(wTth + offB + d);
        bl[cb ^ 1] = *(const bf16x8*)(wTtl + offB + d);
      }
      acc =
          __builtin_amdgcn_mfma_f32_32x32x16_bf16(ah[cb], bh[cb], acc, 0, 0, 0);
      acc =
          __builtin_amdgcn_mfma_f32_32x32x16_bf16(ah[cb], bl[cb], acc, 0, 0, 0);
      acc =
          __builtin_amdgcn_mfma_f32_32x32x16_bf16(al[cb], bh[cb], acc, 0, 0, 0);
    }
    const float beta = beta_p[0];
    const float ombeta = 1.0f - beta;
    const int col = o0 + wn * 32 + lm;
#pragma unroll
    for (int r = 0; r < 16; ++r) {
      int row = i0 + wm * 32 + (r & 3) + 8 * (r >> 2) + 4 * lkh;
      M[(size_t)row * O_DIM + col] =
          ombeta * v[(size_t)row * O_DIM + col] - beta * acc[r];
    }
  }
}

// ---------------------------------------------------------------------------
// Scan R15: adjacent-neuron assignment o = {2*tid, 2*tid+1}. Every M-gather
// access is now ONE float2 wave-load (512B) instead of two strided float
// wave-loads (2x256B): same bytes, half the requests + half the addr VALU.
// Discriminates byte-limited vs request-limited L1: big gain only if
// request-limited. h-loads and out-stores also float2. wlist semantics
// unchanged (stores neuron index); entry order changes (even then odd per
// wave) -- double-sum re-association, proven absmax-safe in R8/R14.
// 4-way row unroll kept from R14 (harmless).
// ---------------------------------------------------------------------------
__global__ __launch_bounds__(512) void scan_kernel(
    const float* __restrict__ h, const float* __restrict__ M,
    const double* __restrict__ normpart, const float* __restrict__ bvec,
    const float* __restrict__ beta_p, float* __restrict__ out,
    int* __restrict__ wgcnt) {
  __shared__ unsigned short wlist[2][8][128];
  __shared__ int wcnt[2][8];
  const int b = blockIdx.x, tid = threadIdx.x;
  const int wv = tid >> 6;  // 0..7
  const int o0 = tid * 2;   // adjacent pair {o0, o0+1}
  const double beta = (double)beta_p[0];
  const double ombeta = 1.0 - beta;
  double mem[2] = {0.0, 0.0};
  double inv[2], bth[2];
  {
    double s0 = 0.0, s1 = 0.0;
#pragma unroll
    for (int g = 0; g < 16; ++g) {
      double2 np = *(const double2*)&normpart[(size_t)g * O_DIM + o0];
      s0 += np.x;
      s1 += np.y;
    }
    inv[0] = 1.0 / (s0 + 1e-8);
    inv[1] = 1.0 / (s1 + 1e-8);
    float2 bv = *(const float2*)&bvec[o0];
    bth[0] = (double)bv.x;
    bth[1] = (double)bv.y;
  }
  if (tid < 16) wcnt[tid >> 3][tid & 7] = 0;
  __syncthreads();
  const float* hb = h + (size_t)b * T_DIM * O_DIM;
  float* ob = out + (size_t)b * T_DIM * O_DIM;
  float2 hv0 = *(const float2*)&hb[o0];
  float2 hv1 = *(const float2*)&hb[O_DIM + o0];
  for (int t = 0; t < T_DIM; ++t) {
    const int p = t & 1, np = p ^ 1;
    float2 hv2 = make_float2(0.f, 0.f);
    if (t + 2 < T_DIM) hv2 = *(const float2*)&hb[(size_t)(t + 2) * O_DIM + o0];
    double l0[2] = {0.0, 0.0}, l1[2] = {0.0, 0.0};
    double l2[2] = {0.0, 0.0}, l3[2] = {0.0, 0.0};
    int ks = 0;
#pragma unroll
    for (int w = 0; w < 8; ++w) ks += wcnt[p][w];
    if (ks) {
#pragma unroll
      for (int w = 0; w < 8; ++w) {
        const int kw = wcnt[p][w];
        const unsigned short* wl = wlist[p][w];
        int n = 0;
        for (; n + 4 <= kw; n += 4) {
          float2 m0 = *(const float2*)&M[(size_t)wl[n] * O_DIM + o0];
          float2 m1 = *(const float2*)&M[(size_t)wl[n + 1] * O_DIM + o0];
          float2 m2 = *(const float2*)&M[(size_t)wl[n + 2] * O_DIM + o0];
          float2 m3 = *(const float2*)&M[(size_t)wl[n + 3] * O_DIM + o0];
          l0[0] += (double)m0.x;
          l0[1] += (double)m0.y;
          l1[0] += (double)m1.x;
          l1[1] += (double)m1.y;
          l2[0] += (double)m2.x;
          l2[1] += (double)m2.y;
          l3[0] += (double)m3.x;
          l3[1] += (double)m3.y;
        }
        for (; n < kw; ++n) {
          float2 mr = *(const float2*)&M[(size_t)wl[n] * O_DIM + o0];
          l0[0] += (double)mr.x;
          l0[1] += (double)mr.y;
        }
      }
    }
    // membrane update + spike decisions for both adjacent neurons
    double lat0 = (l0[0] + l1[0]) + (l2[0] + l3[0]);
    double lat1 = (l0[1] + l1[1]) + (l2[1] + l3[1]);
    mem[0] = mem[0] * beta + (double)hv0.x * ombeta + lat0;
    mem[1] = mem[1] * beta + (double)hv0.y * ombeta + lat1;
    bool s0 = (mem[0] * inv[0] - bth[0]) > 0.0;
    bool s1 = (mem[1] * inv[1] - bth[1]) > 0.0;
    *(float2*)&ob[(size_t)t * O_DIM + o0] =
        make_float2(s0 ? 1.0f : 0.0f, s1 ? 1.0f : 0.0f);
    unsigned cur = 0;
    {
      unsigned long long mask = __ballot(s0);
      if (s0) {
        unsigned below = __builtin_amdgcn_mbcnt_lo((unsigned)mask, 0);
        below = __builtin_amdgcn_mbcnt_hi((unsigned)(mask >> 32), below);
        wlist[np][wv][cur + below] = (unsigned short)o0;
      }
      cur += (unsigned)__popcll(mask);
    }
    {
      unsigned long long mask = __ballot(s1);
      if (s1) {
        unsigned below = __builtin_amdgcn_mbcnt_lo((unsigned)mask, 0);
        below = __builtin_amdgcn_mbcnt_hi((unsigned)(mask >> 32), below);
        wlist[np][wv][cur + below] = (unsigned short)(o0 + 1);
      }
      cur += (unsigned)__popcll(mask);
    }
    hv0 = hv1;
    hv1 = hv2;
    if ((tid & 63) == 0) wcnt[np][wv] = (int)cur;
    wg_barrier_lgkm();
    if (tid == 0)
      wgcnt[b * T_DIM + t] = wcnt[np][0] + wcnt[np][1] + wcnt[np][2] +
                             wcnt[np][3] + wcnt[np][4] + wcnt[np][5] +
                             wcnt[np][6] + wcnt[np][7];
  }
}

// ---------------------------------------------------------------------------
// finalize: counts[t] = sum_b wgcnt[b][t]; loss & spread from exact ints.
// ---------------------------------------------------------------------------
__global__ void finalize_kernel(const int* __restrict__ wgcnt,
                                float* __restrict__ out) {
  __shared__ int sums[128];
  const int t = threadIdx.x;  // 128 threads
  int s = 0;
  if (t < T_DIM) {
    for (int b = 0; b < B_DIM; ++b) s += wgcnt[b * T_DIM + t];
  }
  sums[t] = s;
  __syncthreads();
  if (t == 0) {
    long long total = 0;
    int mx = 0;
    for (int i = 0; i < T_DIM; ++i) {
      total += sums[i];
      if (sums[i] > mx) mx = sums[i];
    }
    const double N = (double)B_DIM * T_DIM * O_DIM;
    out[(size_t)B_DIM * T_DIM * O_DIM] = (float)(0.5 * (double)total / N);
    out[(size_t)B_DIM * T_DIM * O_DIM + 1] =
        (float)((double)mx / (double)(B_DIM * O_DIM));
  }
}

extern "C" void kernel_launch(void* const* d_in, const int* in_sizes, int n_in,
                              void* d_out, int out_size, void* d_ws,
                              size_t ws_size, hipStream_t stream) {
  const float* x = (const float*)d_in[0];
  const float* w = (const float*)d_in[1];
  const float* v = (const float*)d_in[2];
  const float* beta = (const float*)d_in[3];
  const float* b = (const float*)d_in[4];
  float* out = (float*)d_out;

  char* ws = (char*)d_ws;
  const size_t OFF_M = 0;           // 4 MB
  const size_t OFF_H = 4194304;     // 50 MB
  const size_t OFF_WTH = 56623104;  // 2 MB
  const size_t OFF_WTL = 58720256;  // 2 MB
  const size_t OFF_NP = 60817408;   // 128 KB
  const size_t OFF_XTH = 60948992;  // 25 MB
  const size_t OFF_XTL = 87163392;  // 25 MB -> end 113377792 (proven fits)
  float* M = (float*)(ws + OFF_M);
  float* h = (float*)(ws + OFF_H);
  unsigned short* wTth = (unsigned short*)(ws + OFF_WTH);
  unsigned short* wTtl = (unsigned short*)(ws + OFF_WTL);
  double* normpart = (double*)(ws + OFF_NP);
  unsigned short* xth = (unsigned short*)(ws + OFF_XTH);
  unsigned short* xtl = (unsigned short*)(ws + OFF_XTL);
  // wgcnt reuses the (dead-by-then) xth region: gemm finished before scan.
  int* wgcnt = (int*)(ws + OFF_XTH);

  hipLaunchKernelGGL(prep_kernel, dim3(656), dim3(256), 0, stream, w, x, wTth,
                     wTtl, xth, xtl, normpart);
  hipLaunchKernelGGL(gemm_fused, dim3(16, 116), dim3(256), 0, stream, xth, xtl,
                     wTth, wTtl, v, beta, h, M);
  hipLaunchKernelGGL(scan_kernel, dim3(128), dim3(512), 0, stream, h, M,
                     normpart, b, beta, out, wgcnt);
  hipLaunchKernelGGL(finalize_kernel, dim3(1), dim3(128), 0, stream, wgcnt,
                     out);
}

// Round 21
// 297.095 us; speedup vs baseline: 1.0220x; 1.0097x over previous
//
#include <hip/hip_runtime.h>
#include <cstdint>
#include <cstddef>

#define I_DIM 1024
#define O_DIM 1024
#define B_DIM 128
#define T_DIM 100
#define PANEL 32768  // fragment-tiled panel stride (ushorts) = 64q*64lane*8
#define QSTep 512    // per-q stride (ushorts) = 64 lanes * 8

typedef __attribute__((ext_vector_type(8))) __bf16 bf16x8;
typedef __attribute__((ext_vector_type(16))) float f32x16;

// Workgroup barrier that drains only LDS ops (lgkmcnt=0); global loads and
// stores stay in flight. simm16 = vm[3:0]=0xF | exp=7<<4 | lgkm=0<<8 |
// vm[5:4]=3<<14 = 0xC07F.
__device__ __forceinline__ void wg_barrier_lgkm() {
  __asm__ volatile("" ::: "memory");
  __builtin_amdgcn_s_waitcnt(0xC07F);
  __builtin_amdgcn_s_barrier();
  __asm__ volatile("" ::: "memory");
}

__device__ __forceinline__ unsigned short bf16rn(float x) {
  unsigned u = __float_as_uint(x);
  unsigned r = u + 0x7FFFu + ((u >> 16) & 1u);
  return (unsigned short)(r >> 16);
}
__device__ __forceinline__ void split2(float x, unsigned short& h,
                                       unsigned short& l) {
  h = bf16rn(x);
  float hf = __uint_as_float(((unsigned)h) << 16);
  l = bf16rn(x - hf);
}

// ---------------------------------------------------------------------------
// prep: fused split_wT (WGs 0..255) + xsplit (WGs 256..655).
// ---------------------------------------------------------------------------
__global__ __launch_bounds__(256) void prep_kernel(
    const float* __restrict__ w, const float* __restrict__ x,
    unsigned short* __restrict__ wTth, unsigned short* __restrict__ wTtl,
    unsigned short* __restrict__ xth, unsigned short* __restrict__ xtl,
    double* __restrict__ normpart) {
  __shared__ float tile[64][65];
  __shared__ double red[4][64];
  const int id = blockIdx.x;
  const int tid = threadIdx.x;
  if (id < 256) {  // ---- split_wT ----
    const int a0 = (id >> 4) * 64, o0 = (id & 15) * 64;
    const int tr = tid >> 4, tc4 = (tid & 15) * 4;
#pragma unroll
    for (int rr = 0; rr < 64; rr += 16) {
      float4 v = *(const float4*)&w[(size_t)(a0 + tr + rr) * O_DIM + o0 + tc4];
      tile[tr + rr][tc4 + 0] = v.x;
      tile[tr + rr][tc4 + 1] = v.y;
      tile[tr + rr][tc4 + 2] = v.z;
      tile[tr + rr][tc4 + 3] = v.w;
    }
    __syncthreads();
    {
      const int ol = tid & 63, seg = tid >> 6;
      double s = 0.0;
#pragma unroll
      for (int i = 0; i < 16; ++i) {
        double v = (double)tile[seg * 16 + i][ol];
        s += v * v;
      }
      red[seg][ol] = s;
    }
    const int q = (a0 >> 4) + (tc4 >> 4);
    const int kh = (tc4 >> 3) & 1;
    const int inner = tc4 & 7;
#pragma unroll
    for (int rr = 0; rr < 64; rr += 16) {
      int o = o0 + tr + rr;
      unsigned short hh[4], ll[4];
#pragma unroll
      for (int j = 0; j < 4; ++j) split2(tile[tc4 + j][tr + rr], hh[j], ll[j]);
      int l = (o & 31) + 32 * kh;
      size_t base = ((size_t)(o >> 5) * PANEL) + (size_t)q * QSTep +
                    (size_t)l * 8 + inner;
      *(ushort4*)&wTth[base] = make_ushort4(hh[0], hh[1], hh[2], hh[3]);
      *(ushort4*)&wTtl[base] = make_ushort4(ll[0], ll[1], ll[2], ll[3]);
    }
    __syncthreads();
    if (tid < 64)
      normpart[(size_t)(a0 >> 6) * O_DIM + o0 + tid] =
          red[0][tid] + red[1][tid] + red[2][tid] + red[3][tid];
  } else {  // ---- xsplit ----
    const int p = id - 256;
    const int wq = tid >> 6, lane = tid & 63;
    const int row = lane & 31, kh = lane >> 5;
    const float* src = x + (size_t)(p * 32 + row) * I_DIM + kh * 8;
#pragma unroll 4
    for (int i = 0; i < 16; ++i) {
      const int q = i * 4 + wq;
      const float* s = src + q * 16;
      float4 v0 = *(const float4*)(s);
      float4 v1 = *(const float4*)(s + 4);
      unsigned short h[8], l[8];
      split2(v0.x, h[0], l[0]);
      split2(v0.y, h[1], l[1]);
      split2(v0.z, h[2], l[2]);
      split2(v0.w, h[3], l[3]);
      split2(v1.x, h[4], l[4]);
      split2(v1.y, h[5], l[5]);
      split2(v1.z, h[6], l[6]);
      split2(v1.w, h[7], l[7]);
      size_t base = ((size_t)p * PANEL) + (size_t)q * QSTep + (size_t)lane * 8;
      *(ushort4*)&xth[base] = make_ushort4(h[0], h[1], h[2], h[3]);
      *(ushort4*)&xth[base + 4] = make_ushort4(h[4], h[5], h[6], h[7]);
      *(ushort4*)&xtl[base] = make_ushort4(l[0], l[1], l[2], l[3]);
      *(ushort4*)&xtl[base + 4] = make_ushort4(l[4], l[5], l[6], l[7]);
    }
  }
}

// ---------------------------------------------------------------------------
// gemm_fused R18: hgemm now LDS-staged. Per q-step the WG cooperatively
// stages the UNIQUE 12KB slice (A-hi/lo: 4 panels x 1KB each; B-hi/lo: 2
// panels x 1KB each) via reg-staging (uint4), then waves ds_read_b128 their
// fragments. Halves L2 traffic (was 24KB/WG/q with 2x wave duplication;
// hgemm was ~25 TB/s = 75% of L2 ceiling). Two barriers per q-step; q+1
// global loads issue during the MFMA phase (latency hidden). Per-accumulator
// MFMA order (q asc; hh,hl,lh) and input values identical -> bit-identical h.
// mbuild unchanged (validated).
// LDS layout (ushorts): A-hi [0,2048) panel p at p*512; A-lo [2048,4096);
// B-hi [4096,5120) panel p at 4096+p*512; B-lo [5120,6144).
// Staging: thread tid owns chunk tid (A-hi), tid+256 (A-lo), and
// tid<128 ? B-hi chunk tid : B-lo chunk tid-128. Chunk c of a region:
// panel p=c>>6, ushort offset (c&63)*8 -> 16B contiguous per thread.
// ---------------------------------------------------------------------------
__global__ __launch_bounds__(256) void gemm_fused(
    const unsigned short* __restrict__ xth,
    const unsigned short* __restrict__ xtl,
    const unsigned short* __restrict__ wTth,
    const unsigned short* __restrict__ wTtl, const float* __restrict__ v,
    const float* __restrict__ beta_p, float* __restrict__ h,
    float* __restrict__ M) {
  __shared__ __align__(16) unsigned short sbuf[6144];  // 12 KB
  const int tid = threadIdx.x;
  const int wv = tid >> 6, lane = tid & 63;
  const int lm = lane & 31, lkh = lane >> 5;
  if (blockIdx.y < 100) {  // ---------------- hgemm ----------------
    const int lin = blockIdx.y * 16 + blockIdx.x;  // [0,1600)
    const int slin = (lin & 7) * 200 + (lin >> 3);
    const int row0 = (slin >> 4) * 128, col0 = (slin & 15) * 64;
    const int wm = wv >> 1, wn = wv & 1;
    f32x16 acc[2];
#pragma unroll
    for (int a = 0; a < 2; ++a)
#pragma unroll
      for (int e = 0; e < 16; ++e) acc[a][e] = 0.f;
    // staging sources (panel base + within-slice offset; add q*QSTep later)
    const unsigned short* gs0;  // A-hi
    const unsigned short* gs1;  // A-lo
    const unsigned short* gs2;  // B-hi or B-lo
    int lo0, lo1, lo2;
    {
      const int p = tid >> 6, w16 = (tid & 63) * 8;
      gs0 = xth + ((size_t)((row0 >> 5) + p) * PANEL) + w16;
      gs1 = xtl + ((size_t)((row0 >> 5) + p) * PANEL) + w16;
      lo0 = tid * 8;
      lo1 = 2048 + tid * 8;
      if (tid < 128) {
        const int pp = tid >> 6, ww = (tid & 63) * 8;
        gs2 = wTth + ((size_t)((col0 >> 5) + pp) * PANEL) + ww;
        lo2 = 4096 + tid * 8;
      } else {
        const int tb = tid - 128;
        const int pp = tb >> 6, ww = (tb & 63) * 8;
        gs2 = wTtl + ((size_t)((col0 >> 5) + pp) * PANEL) + ww;
        lo2 = 5120 + tb * 8;
      }
    }
    uint4 r0 = *(const uint4*)(gs0);
    uint4 r1 = *(const uint4*)(gs1);
    uint4 r2 = *(const uint4*)(gs2);
    // per-wave fragment LDS offsets (ushorts)
    const int fa0 = (wm * 2 + 0) * 512 + lane * 8;
    const int fa1 = (wm * 2 + 1) * 512 + lane * 8;
    const int fb = 4096 + wn * 512 + lane * 8;
    for (int q = 0; q < 64; ++q) {
      *(uint4*)&sbuf[lo0] = r0;
      *(uint4*)&sbuf[lo1] = r1;
      *(uint4*)&sbuf[lo2] = r2;
      __syncthreads();
      if (q < 63) {
        size_t d = (size_t)(q + 1) * QSTep;
        r0 = *(const uint4*)(gs0 + d);
        r1 = *(const uint4*)(gs1 + d);
        r2 = *(const uint4*)(gs2 + d);
      }
      bf16x8 fah[2], fal[2], fbh, fbl;
      fah[0] = *(const bf16x8*)&sbuf[fa0];
      fah[1] = *(const bf16x8*)&sbuf[fa1];
      fal[0] = *(const bf16x8*)&sbuf[2048 + fa0];
      fal[1] = *(const bf16x8*)&sbuf[2048 + fa1];
      fbh = *(const bf16x8*)&sbuf[fb];
      fbl = *(const bf16x8*)&sbuf[1024 + fb];
#pragma unroll
      for (int mt = 0; mt < 2; ++mt)
        acc[mt] = __builtin_amdgcn_mfma_f32_32x32x16_bf16(fah[mt], fbh, acc[mt],
                                                          0, 0, 0);
#pragma unroll
      for (int mt = 0; mt < 2; ++mt)
        acc[mt] = __builtin_amdgcn_mfma_f32_32x32x16_bf16(fah[mt], fbl, acc[mt],
                                                          0, 0, 0);
#pragma unroll
      for (int mt = 0; mt < 2; ++mt)
        acc[mt] = __builtin_amdgcn_mfma_f32_32x32x16_bf16(fal[mt], fbh, acc[mt],
                                                          0, 0, 0);
      __syncthreads();
    }
    const int col = col0 + wn * 32 + lm;
#pragma unroll
    for (int mt = 0; mt < 2; ++mt)
#pragma unroll
      for (int r = 0; r < 16; ++r) {
        int row = row0 + wm * 64 + mt * 32 + (r & 3) + 8 * (r >> 2) + 4 * lkh;
        h[(size_t)row * O_DIM + col] = acc[mt][r];
      }
  } else {  // ---------------- mbuild (validated R1 form) ----------------
    const int i0 = (blockIdx.y - 100) * 64, o0 = blockIdx.x * 64;
    const int wm = wv >> 1, wn = wv & 1;
    f32x16 acc;
#pragma unroll
    for (int e = 0; e < 16; ++e) acc[e] = 0.f;
    const size_t offA = ((size_t)((i0 >> 5) + wm) * PANEL) + (size_t)lane * 8;
    const size_t offB = ((size_t)((o0 >> 5) + wn) * PANEL) + (size_t)lane * 8;
    bf16x8 ah[2], al[2], bh[2], bl[2];
    ah[0] = *(const bf16x8*)(wTth + offA);
    al[0] = *(const bf16x8*)(wTtl + offA);
    bh[0] = *(const bf16x8*)(wTth + offB);
    bl[0] = *(const bf16x8*)(wTtl + offB);
#pragma unroll 2
    for (int q = 0; q < 64; ++q) {
      const int cb = q & 1;
      if (q < 63) {
        size_t d = (size_t)(q + 1) * QSTep;
        ah[cb ^ 1] = *(const bf16x8*)(wTth + offA + d);
        al[cb ^ 1] = *(const bf16x8*)(wTtl + offA + d);
        bh[cb ^ 1] = *(const bf16x8*)(wTth + offB + d);
        bl[cb ^ 1] = *(const bf16x8*)(wTtl + offB + d);
      }
      acc =
          __builtin_amdgcn_mfma_f32_32x32x16_bf16(ah[cb], bh[cb], acc, 0, 0, 0);
      acc =
          __builtin_amdgcn_mfma_f32_32x32x16_bf16(ah[cb], bl[cb], acc, 0, 0, 0);
      acc =
          __builtin_amdgcn_mfma_f32_32x32x16_bf16(al[cb], bh[cb], acc, 0, 0, 0);
    }
    const float beta = beta_p[0];
    const float ombeta = 1.0f - beta;
    const int col = o0 + wn * 32 + lm;
#pragma unroll
    for (int r = 0; r < 16; ++r) {
      int row = i0 + wm * 32 + (r & 3) + 8 * (r >> 2) + 4 * lkh;
      M[(size_t)row * O_DIM + col] =
          ombeta * v[(size_t)row * O_DIM + col] - beta * acc[r];
    }
  }
}

// ---------------------------------------------------------------------------
// Scan R15 (validated: byte-limited floor; float2 adjacent-neuron gather).
// ---------------------------------------------------------------------------
__global__ __launch_bounds__(512) void scan_kernel(
    const float* __restrict__ h, const float* __restrict__ M,
    const double* __restrict__ normpart, const float* __restrict__ bvec,
    const float* __restrict__ beta_p, float* __restrict__ out,
    int* __restrict__ wgcnt) {
  __shared__ unsigned short wlist[2][8][128];
  __shared__ int wcnt[2][8];
  const int b = blockIdx.x, tid = threadIdx.x;
  const int wv = tid >> 6;  // 0..7
  const int o0 = tid * 2;   // adjacent pair {o0, o0+1}
  const double beta = (double)beta_p[0];
  const double ombeta = 1.0 - beta;
  double mem[2] = {0.0, 0.0};
  double inv[2], bth[2];
  {
    double s0 = 0.0, s1 = 0.0;
#pragma unroll
    for (int g = 0; g < 16; ++g) {
      double2 np = *(const double2*)&normpart[(size_t)g * O_DIM + o0];
      s0 += np.x;
      s1 += np.y;
    }
    inv[0] = 1.0 / (s0 + 1e-8);
    inv[1] = 1.0 / (s1 + 1e-8);
    float2 bv = *(const float2*)&bvec[o0];
    bth[0] = (double)bv.x;
    bth[1] = (double)bv.y;
  }
  if (tid < 16) wcnt[tid >> 3][tid & 7] = 0;
  __syncthreads();
  const float* hb = h + (size_t)b * T_DIM * O_DIM;
  float* ob = out + (size_t)b * T_DIM * O_DIM;
  float2 hv0 = *(const float2*)&hb[o0];
  float2 hv1 = *(const float2*)&hb[O_DIM + o0];
  for (int t = 0; t < T_DIM; ++t) {
    const int p = t & 1, np = p ^ 1;
    float2 hv2 = make_float2(0.f, 0.f);
    if (t + 2 < T_DIM) hv2 = *(const float2*)&hb[(size_t)(t + 2) * O_DIM + o0];
    double l0[2] = {0.0, 0.0}, l1[2] = {0.0, 0.0};
    double l2[2] = {0.0, 0.0}, l3[2] = {0.0, 0.0};
    int ks = 0;
#pragma unroll
    for (int w = 0; w < 8; ++w) ks += wcnt[p][w];
    if (ks) {
#pragma unroll
      for (int w = 0; w < 8; ++w) {
        const int kw = wcnt[p][w];
        const unsigned short* wl = wlist[p][w];
        int n = 0;
        for (; n + 4 <= kw; n += 4) {
          float2 m0 = *(const float2*)&M[(size_t)wl[n] * O_DIM + o0];
          float2 m1 = *(const float2*)&M[(size_t)wl[n + 1] * O_DIM + o0];
          float2 m2 = *(const float2*)&M[(size_t)wl[n + 2] * O_DIM + o0];
          float2 m3 = *(const float2*)&M[(size_t)wl[n + 3] * O_DIM + o0];
          l0[0] += (double)m0.x;
          l0[1] += (double)m0.y;
          l1[0] += (double)m1.x;
          l1[1] += (double)m1.y;
          l2[0] += (double)m2.x;
          l2[1] += (double)m2.y;
          l3[0] += (double)m3.x;
          l3[1] += (double)m3.y;
        }
        for (; n < kw; ++n) {
          float2 mr = *(const float2*)&M[(size_t)wl[n] * O_DIM + o0];
          l0[0] += (double)mr.x;
          l0[1] += (double)mr.y;
        }
      }
    }
    double lat0 = (l0[0] + l1[0]) + (l2[0] + l3[0]);
    double lat1 = (l0[1] + l1[1]) + (l2[1] + l3[1]);
    mem[0] = mem[0] * beta + (double)hv0.x * ombeta + lat0;
    mem[1] = mem[1] * beta + (double)hv0.y * ombeta + lat1;
    bool s0 = (mem[0] * inv[0] - bth[0]) > 0.0;
    bool s1 = (mem[1] * inv[1] - bth[1]) > 0.0;
    *(float2*)&ob[(size_t)t * O_DIM + o0] =
        make_float2(s0 ? 1.0f : 0.0f, s1 ? 1.0f : 0.0f);
    unsigned cur = 0;
    {
      unsigned long long mask = __ballot(s0);
      if (s0) {
        unsigned below = __builtin_amdgcn_mbcnt_lo((unsigned)mask, 0);
        below = __builtin_amdgcn_mbcnt_hi((unsigned)(mask >> 32), below);
        wlist[np][wv][cur + below] = (unsigned short)o0;
      }
      cur += (unsigned)__popcll(mask);
    }
    {
      unsigned long long mask = __ballot(s1);
      if (s1) {
        unsigned below = __builtin_amdgcn_mbcnt_lo((unsigned)mask, 0);
        below = __builtin_amdgcn_mbcnt_hi((unsigned)(mask >> 32), below);
        wlist[np][wv][cur + below] = (unsigned short)(o0 + 1);
      }
      cur += (unsigned)__popcll(mask);
    }
    hv0 = hv1;
    hv1 = hv2;
    if ((tid & 63) == 0) wcnt[np][wv] = (int)cur;
    wg_barrier_lgkm();
    if (tid == 0)
      wgcnt[b * T_DIM + t] = wcnt[np][0] + wcnt[np][1] + wcnt[np][2] +
                             wcnt[np][3] + wcnt[np][4] + wcnt[np][5] +
                             wcnt[np][6] + wcnt[np][7];
  }
}

// ---------------------------------------------------------------------------
// finalize: counts[t] = sum_b wgcnt[b][t]; loss & spread from exact ints.
// ---------------------------------------------------------------------------
__global__ void finalize_kernel(const int* __restrict__ wgcnt,
                                float* __restrict__ out) {
  __shared__ int sums[128];
  const int t = threadIdx.x;  // 128 threads
  int s = 0;
  if (t < T_DIM) {
    for (int b = 0; b < B_DIM; ++b) s += wgcnt[b * T_DIM + t];
  }
  sums[t] = s;
  __syncthreads();
  if (t == 0) {
    long long total = 0;
    int mx = 0;
    for (int i = 0; i < T_DIM; ++i) {
      total += sums[i];
      if (sums[i] > mx) mx = sums[i];
    }
    const double N = (double)B_DIM * T_DIM * O_DIM;
    out[(size_t)B_DIM * T_DIM * O_DIM] = (float)(0.5 * (double)total / N);
    out[(size_t)B_DIM * T_DIM * O_DIM + 1] =
        (float)((double)mx / (double)(B_DIM * O_DIM));
  }
}

extern "C" void kernel_launch(void* const* d_in, const int* in_sizes, int n_in,
                              void* d_out, int out_size, void* d_ws,
                              size_t ws_size, hipStream_t stream) {
  const float* x = (const float*)d_in[0];
  const float* w = (const float*)d_in[1];
  const float* v = (const float*)d_in[2];
  const float* beta = (const float*)d_in[3];
  const float* b = (const float*)d_in[4];
  float* out = (float*)d_out;

  char* ws = (char*)d_ws;
  const size_t OFF_M = 0;           // 4 MB
  const size_t OFF_H = 4194304;     // 50 MB
  const size_t OFF_WTH = 56623104;  // 2 MB
  const size_t OFF_WTL = 58720256;  // 2 MB
  const size_t OFF_NP = 60817408;   // 128 KB
  const size_t OFF_XTH = 60948992;  // 25 MB
  const size_t OFF_XTL = 87163392;  // 25 MB -> end 113377792 (proven fits)
  float* M = (float*)(ws + OFF_M);
  float* h = (float*)(ws + OFF_H);
  unsigned short* wTth = (unsigned short*)(ws + OFF_WTH);
  unsigned short* wTtl = (unsigned short*)(ws + OFF_WTL);
  double* normpart = (double*)(ws + OFF_NP);
  unsigned short* xth = (unsigned short*)(ws + OFF_XTH);
  unsigned short* xtl = (unsigned short*)(ws + OFF_XTL);
  // wgcnt reuses the (dead-by-then) xth region: gemm finished before scan.
  int* wgcnt = (int*)(ws + OFF_XTH);

  hipLaunchKernelGGL(prep_kernel, dim3(656), dim3(256), 0, stream, w, x, wTth,
                     wTtl, xth, xtl, normpart);
  hipLaunchKernelGGL(gemm_fused, dim3(16, 116), dim3(256), 0, stream, xth, xtl,
                     wTth, wTtl, v, beta, h, M);
  hipLaunchKernelGGL(scan_kernel, dim3(128), dim3(512), 0, stream, h, M,
                     normpart, b, beta, out, wgcnt);
  hipLaunchKernelGGL(finalize_kernel, dim3(1), dim3(128), 0, stream, wgcnt,
                     out);
}

// Round 25
// 288.141 us; speedup vs baseline: 1.0537x; 1.0311x over previous
//
#include <hip/hip_runtime.h>
#include <cstdint>
#include <cstddef>

#define I_DIM 1024
#define O_DIM 1024
#define B_DIM 128
#define T_DIM 100
#define PANEL 32768  // fragment-tiled panel stride (ushorts) = 64q*64lane*8
#define QSTep 512    // per-q stride (ushorts) = 64 lanes * 8

typedef __attribute__((ext_vector_type(8))) __bf16 bf16x8;
typedef __attribute__((ext_vector_type(16))) float f32x16;

// Workgroup barrier that drains only LDS ops (lgkmcnt=0); global loads and
// stores stay in flight. simm16 = vm[3:0]=0xF | exp=7<<4 | lgkm=0<<8 |
// vm[5:4]=3<<14 = 0xC07F.
__device__ __forceinline__ void wg_barrier_lgkm() {
  __asm__ volatile("" ::: "memory");
  __builtin_amdgcn_s_waitcnt(0xC07F);
  __builtin_amdgcn_s_barrier();
  __asm__ volatile("" ::: "memory");
}

__device__ __forceinline__ unsigned short bf16rn(float x) {
  unsigned u = __float_as_uint(x);
  unsigned r = u + 0x7FFFu + ((u >> 16) & 1u);
  return (unsigned short)(r >> 16);
}
__device__ __forceinline__ void split2(float x, unsigned short& h,
                                       unsigned short& l) {
  h = bf16rn(x);
  float hf = __uint_as_float(((unsigned)h) << 16);
  l = bf16rn(x - hf);
}

// ---------------------------------------------------------------------------
// prep: fused split_wT (WGs 0..255) + xsplit (WGs 256..655).
// ---------------------------------------------------------------------------
__global__ __launch_bounds__(256) void prep_kernel(
    const float* __restrict__ w, const float* __restrict__ x,
    unsigned short* __restrict__ wTth, unsigned short* __restrict__ wTtl,
    unsigned short* __restrict__ xth, unsigned short* __restrict__ xtl,
    double* __restrict__ normpart) {
  __shared__ float tile[64][65];
  __shared__ double red[4][64];
  const int id = blockIdx.x;
  const int tid = threadIdx.x;
  if (id < 256) {  // ---- split_wT ----
    const int a0 = (id >> 4) * 64, o0 = (id & 15) * 64;
    const int tr = tid >> 4, tc4 = (tid & 15) * 4;
#pragma unroll
    for (int rr = 0; rr < 64; rr += 16) {
      float4 v = *(const float4*)&w[(size_t)(a0 + tr + rr) * O_DIM + o0 + tc4];
      tile[tr + rr][tc4 + 0] = v.x;
      tile[tr + rr][tc4 + 1] = v.y;
      tile[tr + rr][tc4 + 2] = v.z;
      tile[tr + rr][tc4 + 3] = v.w;
    }
    __syncthreads();
    {
      const int ol = tid & 63, seg = tid >> 6;
      double s = 0.0;
#pragma unroll
      for (int i = 0; i < 16; ++i) {
        double v = (double)tile[seg * 16 + i][ol];
        s += v * v;
      }
      red[seg][ol] = s;
    }
    const int q = (a0 >> 4) + (tc4 >> 4);
    const int kh = (tc4 >> 3) & 1;
    const int inner = tc4 & 7;
#pragma unroll
    for (int rr = 0; rr < 64; rr += 16) {
      int o = o0 + tr + rr;
      unsigned short hh[4], ll[4];
#pragma unroll
      for (int j = 0; j < 4; ++j) split2(tile[tc4 + j][tr + rr], hh[j], ll[j]);
      int l = (o & 31) + 32 * kh;
      size_t base = ((size_t)(o >> 5) * PANEL) + (size_t)q * QSTep +
                    (size_t)l * 8 + inner;
      *(ushort4*)&wTth[base] = make_ushort4(hh[0], hh[1], hh[2], hh[3]);
      *(ushort4*)&wTtl[base] = make_ushort4(ll[0], ll[1], ll[2], ll[3]);
    }
    __syncthreads();
    if (tid < 64)
      normpart[(size_t)(a0 >> 6) * O_DIM + o0 + tid] =
          red[0][tid] + red[1][tid] + red[2][tid] + red[3][tid];
  } else {  // ---- xsplit ----
    const int p = id - 256;
    const int wq = tid >> 6, lane = tid & 63;
    const int row = lane & 31, kh = lane >> 5;
    const float* src = x + (size_t)(p * 32 + row) * I_DIM + kh * 8;
#pragma unroll 4
    for (int i = 0; i < 16; ++i) {
      const int q = i * 4 + wq;
      const float* s = src + q * 16;
      float4 v0 = *(const float4*)(s);
      float4 v1 = *(const float4*)(s + 4);
      unsigned short h[8], l[8];
      split2(v0.x, h[0], l[0]);
      split2(v0.y, h[1], l[1]);
      split2(v0.z, h[2], l[2]);
      split2(v0.w, h[3], l[3]);
      split2(v1.x, h[4], l[4]);
      split2(v1.y, h[5], l[5]);
      split2(v1.z, h[6], l[6]);
      split2(v1.w, h[7], l[7]);
      size_t base = ((size_t)p * PANEL) + (size_t)q * QSTep + (size_t)lane * 8;
      *(ushort4*)&xth[base] = make_ushort4(h[0], h[1], h[2], h[3]);
      *(ushort4*)&xth[base + 4] = make_ushort4(h[4], h[5], h[6], h[7]);
      *(ushort4*)&xtl[base] = make_ushort4(l[0], l[1], l[2], l[3]);
      *(ushort4*)&xtl[base + 4] = make_ushort4(l[4], l[5], l[6], l[7]);
    }
  }
}

// ---------------------------------------------------------------------------
// gemm_fused R21: hgemm LDS staging now DOUBLE-BUFFERED (sbuf[2], 24 KB):
// one barrier per q-step instead of two (R18 validated staging itself:
// gemm 129->116, MfmaUtil 29.7->33.3, FETCH 85->78 MB; the second barrier
// was the remaining serialization). Iteration q: issue q+1 global loads
// (land during MFMA) -> ds_read frags from sbuf[q&1] -> MFMA -> write regs
// to sbuf[(q+1)&1] -> single __syncthreads. Read/write buffers never alias
// in-iteration; the barrier drains lgkm so writes are visible and reads
// retired before buffer recycle. Values and per-accumulator MFMA order
// (q asc; hh,hl,lh) identical -> bit-identical h. mbuild unchanged.
// LDS layout per buffer (ushorts): A-hi [0,2048) panel p at p*512;
// A-lo [2048,4096); B-hi [4096,5120); B-lo [5120,6144).
// ---------------------------------------------------------------------------
__global__ __launch_bounds__(256) void gemm_fused(
    const unsigned short* __restrict__ xth,
    const unsigned short* __restrict__ xtl,
    const unsigned short* __restrict__ wTth,
    const unsigned short* __restrict__ wTtl, const float* __restrict__ v,
    const float* __restrict__ beta_p, float* __restrict__ h,
    float* __restrict__ M) {
  __shared__ __align__(16) unsigned short sbuf[2][6144];  // 24 KB
  const int tid = threadIdx.x;
  const int wv = tid >> 6, lane = tid & 63;
  const int lm = lane & 31, lkh = lane >> 5;
  if (blockIdx.y < 100) {  // ---------------- hgemm ----------------
    const int lin = blockIdx.y * 16 + blockIdx.x;  // [0,1600)
    const int slin = (lin & 7) * 200 + (lin >> 3);
    const int row0 = (slin >> 4) * 128, col0 = (slin & 15) * 64;
    const int wm = wv >> 1, wn = wv & 1;
    f32x16 acc[2];
#pragma unroll
    for (int a = 0; a < 2; ++a)
#pragma unroll
      for (int e = 0; e < 16; ++e) acc[a][e] = 0.f;
    // staging sources (panel base + within-slice offset; add q*QSTep later)
    const unsigned short* gs0;  // A-hi
    const unsigned short* gs1;  // A-lo
    const unsigned short* gs2;  // B-hi or B-lo
    int lo0, lo1, lo2;
    {
      const int p = tid >> 6, w16 = (tid & 63) * 8;
      gs0 = xth + ((size_t)((row0 >> 5) + p) * PANEL) + w16;
      gs1 = xtl + ((size_t)((row0 >> 5) + p) * PANEL) + w16;
      lo0 = tid * 8;
      lo1 = 2048 + tid * 8;
      if (tid < 128) {
        const int pp = tid >> 6, ww = (tid & 63) * 8;
        gs2 = wTth + ((size_t)((col0 >> 5) + pp) * PANEL) + ww;
        lo2 = 4096 + tid * 8;
      } else {
        const int tb = tid - 128;
        const int pp = tb >> 6, ww = (tb & 63) * 8;
        gs2 = wTtl + ((size_t)((col0 >> 5) + pp) * PANEL) + ww;
        lo2 = 5120 + tb * 8;
      }
    }
    // prologue: stage q=0 into buffer 0
    uint4 r0 = *(const uint4*)(gs0);
    uint4 r1 = *(const uint4*)(gs1);
    uint4 r2 = *(const uint4*)(gs2);
    *(uint4*)&sbuf[0][lo0] = r0;
    *(uint4*)&sbuf[0][lo1] = r1;
    *(uint4*)&sbuf[0][lo2] = r2;
    __syncthreads();
    // per-wave fragment LDS offsets (ushorts)
    const int fa0 = (wm * 2 + 0) * 512 + lane * 8;
    const int fa1 = (wm * 2 + 1) * 512 + lane * 8;
    const int fb = 4096 + wn * 512 + lane * 8;
    for (int q = 0; q < 64; ++q) {
      const int cb = q & 1;
      if (q < 63) {
        size_t d = (size_t)(q + 1) * QSTep;
        r0 = *(const uint4*)(gs0 + d);
        r1 = *(const uint4*)(gs1 + d);
        r2 = *(const uint4*)(gs2 + d);
      }
      bf16x8 fah[2], fal[2], fbh, fbl;
      fah[0] = *(const bf16x8*)&sbuf[cb][fa0];
      fah[1] = *(const bf16x8*)&sbuf[cb][fa1];
      fal[0] = *(const bf16x8*)&sbuf[cb][2048 + fa0];
      fal[1] = *(const bf16x8*)&sbuf[cb][2048 + fa1];
      fbh = *(const bf16x8*)&sbuf[cb][fb];
      fbl = *(const bf16x8*)&sbuf[cb][1024 + fb];
#pragma unroll
      for (int mt = 0; mt < 2; ++mt)
        acc[mt] = __builtin_amdgcn_mfma_f32_32x32x16_bf16(fah[mt], fbh, acc[mt],
                                                          0, 0, 0);
#pragma unroll
      for (int mt = 0; mt < 2; ++mt)
        acc[mt] = __builtin_amdgcn_mfma_f32_32x32x16_bf16(fah[mt], fbl, acc[mt],
                                                          0, 0, 0);
#pragma unroll
      for (int mt = 0; mt < 2; ++mt)
        acc[mt] = __builtin_amdgcn_mfma_f32_32x32x16_bf16(fal[mt], fbh, acc[mt],
                                                          0, 0, 0);
      if (q < 63) {
        *(uint4*)&sbuf[cb ^ 1][lo0] = r0;
        *(uint4*)&sbuf[cb ^ 1][lo1] = r1;
        *(uint4*)&sbuf[cb ^ 1][lo2] = r2;
      }
      __syncthreads();
    }
    const int col = col0 + wn * 32 + lm;
#pragma unroll
    for (int mt = 0; mt < 2; ++mt)
#pragma unroll
      for (int r = 0; r < 16; ++r) {
        int row = row0 + wm * 64 + mt * 32 + (r & 3) + 8 * (r >> 2) + 4 * lkh;
        h[(size_t)row * O_DIM + col] = acc[mt][r];
      }
  } else {  // ---------------- mbuild (validated R1 form) ----------------
    const int i0 = (blockIdx.y - 100) * 64, o0 = blockIdx.x * 64;
    const int wm = wv >> 1, wn = wv & 1;
    f32x16 acc;
#pragma unroll
    for (int e = 0; e < 16; ++e) acc[e] = 0.f;
    const size_t offA = ((size_t)((i0 >> 5) + wm) * PANEL) + (size_t)lane * 8;
    const size_t offB = ((size_t)((o0 >> 5) + wn) * PANEL) + (size_t)lane * 8;
    bf16x8 ah[2], al[2], bh[2], bl[2];
    ah[0] = *(const bf16x8*)(wTth + offA);
    al[0] = *(const bf16x8*)(wTtl + offA);
    bh[0] = *(const bf16x8*)(wTth + offB);
    bl[0] = *(const bf16x8*)(wTtl + offB);
#pragma unroll 2
    for (int q = 0; q < 64; ++q) {
      const int cb = q & 1;
      if (q < 63) {
        size_t d = (size_t)(q + 1) * QSTep;
        ah[cb ^ 1] = *(const bf16x8*)(wTth + offA + d);
        al[cb ^ 1] = *(const bf16x8*)(wTtl + offA + d);
        bh[cb ^ 1] = *(const bf16x8*)(wTth + offB + d);
        bl[cb ^ 1] = *(const bf16x8*)(wTtl + offB + d);
      }
      acc =
          __builtin_amdgcn_mfma_f32_32x32x16_bf16(ah[cb], bh[cb], acc, 0, 0, 0);
      acc =
          __builtin_amdgcn_mfma_f32_32x32x16_bf16(ah[cb], bl[cb], acc, 0, 0, 0);
      acc =
          __builtin_amdgcn_mfma_f32_32x32x16_bf16(al[cb], bh[cb], acc, 0, 0, 0);
    }
    const float beta = beta_p[0];
    const float ombeta = 1.0f - beta;
    const int col = o0 + wn * 32 + lm;
#pragma unroll
    for (int r = 0; r < 16; ++r) {
      int row = i0 + wm * 32 + (r & 3) + 8 * (r >> 2) + 4 * lkh;
      M[(size_t)row * O_DIM + col] =
          ombeta * v[(size_t)row * O_DIM + col] - beta * acc[r];
    }
  }
}

// ---------------------------------------------------------------------------
// Scan R15 (validated: byte-limited floor; float2 adjacent-neuron gather).
// ---------------------------------------------------------------------------
__global__ __launch_bounds__(512) void scan_kernel(
    const float* __restrict__ h, const float* __restrict__ M,
    const double* __restrict__ normpart, const float* __restrict__ bvec,
    const float* __restrict__ beta_p, float* __restrict__ out,
    int* __restrict__ wgcnt) {
  __shared__ unsigned short wlist[2][8][128];
  __shared__ int wcnt[2][8];
  const int b = blockIdx.x, tid = threadIdx.x;
  const int wv = tid >> 6;  // 0..7
  const int o0 = tid * 2;   // adjacent pair {o0, o0+1}
  const double beta = (double)beta_p[0];
  const double ombeta = 1.0 - beta;
  double mem[2] = {0.0, 0.0};
  double inv[2], bth[2];
  {
    double s0 = 0.0, s1 = 0.0;
#pragma unroll
    for (int g = 0; g < 16; ++g) {
      double2 np = *(const double2*)&normpart[(size_t)g * O_DIM + o0];
      s0 += np.x;
      s1 += np.y;
    }
    inv[0] = 1.0 / (s0 + 1e-8);
    inv[1] = 1.0 / (s1 + 1e-8);
    float2 bv = *(const float2*)&bvec[o0];
    bth[0] = (double)bv.x;
    bth[1] = (double)bv.y;
  }
  if (tid < 16) wcnt[tid >> 3][tid & 7] = 0;
  __syncthreads();
  const float* hb = h + (size_t)b * T_DIM * O_DIM;
  float* ob = out + (size_t)b * T_DIM * O_DIM;
  float2 hv0 = *(const float2*)&hb[o0];
  float2 hv1 = *(const float2*)&hb[O_DIM + o0];
  for (int t = 0; t < T_DIM; ++t) {
    const int p = t & 1, np = p ^ 1;
    float2 hv2 = make_float2(0.f, 0.f);
    if (t + 2 < T_DIM) hv2 = *(const float2*)&hb[(size_t)(t + 2) * O_DIM + o0];
    double l0[2] = {0.0, 0.0}, l1[2] = {0.0, 0.0};
    double l2[2] = {0.0, 0.0}, l3[2] = {0.0, 0.0};
    int ks = 0;
#pragma unroll
    for (int w = 0; w < 8; ++w) ks += wcnt[p][w];
    if (ks) {
#pragma unroll
      for (int w = 0; w < 8; ++w) {
        const int kw = wcnt[p][w];
        const unsigned short* wl = wlist[p][w];
        int n = 0;
        for (; n + 4 <= kw; n += 4) {
          float2 m0 = *(const float2*)&M[(size_t)wl[n] * O_DIM + o0];
          float2 m1 = *(const float2*)&M[(size_t)wl[n + 1] * O_DIM + o0];
          float2 m2 = *(const float2*)&M[(size_t)wl[n + 2] * O_DIM + o0];
          float2 m3 = *(const float2*)&M[(size_t)wl[n + 3] * O_DIM + o0];
          l0[0] += (double)m0.x;
          l0[1] += (double)m0.y;
          l1[0] += (double)m1.x;
          l1[1] += (double)m1.y;
          l2[0] += (double)m2.x;
          l2[1] += (double)m2.y;
          l3[0] += (double)m3.x;
          l3[1] += (double)m3.y;
        }
        for (; n < kw; ++n) {
          float2 mr = *(const float2*)&M[(size_t)wl[n] * O_DIM + o0];
          l0[0] += (double)mr.x;
          l0[1] += (double)mr.y;
        }
      }
    }
    double lat0 = (l0[0] + l1[0]) + (l2[0] + l3[0]);
    double lat1 = (l0[1] + l1[1]) + (l2[1] + l3[1]);
    mem[0] = mem[0] * beta + (double)hv0.x * ombeta + lat0;
    mem[1] = mem[1] * beta + (double)hv0.y * ombeta + lat1;
    bool s0 = (mem[0] * inv[0] - bth[0]) > 0.0;
    bool s1 = (mem[1] * inv[1] - bth[1]) > 0.0;
    *(float2*)&ob[(size_t)t * O_DIM + o0] =
        make_float2(s0 ? 1.0f : 0.0f, s1 ? 1.0f : 0.0f);
    unsigned cur = 0;
    {
      unsigned long long mask = __ballot(s0);
      if (s0) {
        unsigned below = __builtin_amdgcn_mbcnt_lo((unsigned)mask, 0);
        below = __builtin_amdgcn_mbcnt_hi((unsigned)(mask >> 32), below);
        wlist[np][wv][cur + below] = (unsigned short)o0;
      }
      cur += (unsigned)__popcll(mask);
    }
    {
      unsigned long long mask = __ballot(s1);
      if (s1) {
        unsigned below = __builtin_amdgcn_mbcnt_lo((unsigned)mask, 0);
        below = __builtin_amdgcn_mbcnt_hi((unsigned)(mask >> 32), below);
        wlist[np][wv][cur + below] = (unsigned short)(o0 + 1);
      }
      cur += (unsigned)__popcll(mask);
    }
    hv0 = hv1;
    hv1 = hv2;
    if ((tid & 63) == 0) wcnt[np][wv] = (int)cur;
    wg_barrier_lgkm();
    if (tid == 0)
      wgcnt[b * T_DIM + t] = wcnt[np][0] + wcnt[np][1] + wcnt[np][2] +
                             wcnt[np][3] + wcnt[np][4] + wcnt[np][5] +
                             wcnt[np][6] + wcnt[np][7];
  }
}

// ---------------------------------------------------------------------------
// finalize: counts[t] = sum_b wgcnt[b][t]; loss & spread from exact ints.
// ---------------------------------------------------------------------------
__global__ void finalize_kernel(const int* __restrict__ wgcnt,
                                float* __restrict__ out) {
  __shared__ int sums[128];
  const int t = threadIdx.x;  // 128 threads
  int s = 0;
  if (t < T_DIM) {
    for (int b = 0; b < B_DIM; ++b) s += wgcnt[b * T_DIM + t];
  }
  sums[t] = s;
  __syncthreads();
  if (t == 0) {
    long long total = 0;
    int mx = 0;
    for (int i = 0; i < T_DIM; ++i) {
      total += sums[i];
      if (sums[i] > mx) mx = sums[i];
    }
    const double N = (double)B_DIM * T_DIM * O_DIM;
    out[(size_t)B_DIM * T_DIM * O_DIM] = (float)(0.5 * (double)total / N);
    out[(size_t)B_DIM * T_DIM * O_DIM + 1] =
        (float)((double)mx / (double)(B_DIM * O_DIM));
  }
}

extern "C" void kernel_launch(void* const* d_in, const int* in_sizes, int n_in,
                              void* d_out, int out_size, void* d_ws,
                              size_t ws_size, hipStream_t stream) {
  const float* x = (const float*)d_in[0];
  const float* w = (const float*)d_in[1];
  const float* v = (const float*)d_in[2];
  const float* beta = (const float*)d_in[3];
  const float* b = (const float*)d_in[4];
  float* out = (float*)d_out;

  char* ws = (char*)d_ws;
  const size_t OFF_M = 0;           // 4 MB
  const size_t OFF_H = 4194304;     // 50 MB
  const size_t OFF_WTH = 56623104;  // 2 MB
  const size_t OFF_WTL = 58720256;  // 2 MB
  const size_t OFF_NP = 60817408;   // 128 KB
  const size_t OFF_XTH = 60948992;  // 25 MB
  const size_t OFF_XTL = 87163392;  // 25 MB -> end 113377792 (proven fits)
  float* M = (float*)(ws + OFF_M);
  float* h = (float*)(ws + OFF_H);
  unsigned short* wTth = (unsigned short*)(ws + OFF_WTH);
  unsigned short* wTtl = (unsigned short*)(ws + OFF_WTL);
  double* normpart = (double*)(ws + OFF_NP);
  unsigned short* xth = (unsigned short*)(ws + OFF_XTH);
  unsigned short* xtl = (unsigned short*)(ws + OFF_XTL);
  // wgcnt reuses the (dead-by-then) xth region: gemm finished before scan.
  int* wgcnt = (int*)(ws + OFF_XTH);

  hipLaunchKernelGGL(prep_kernel, dim3(656), dim3(256), 0, stream, w, x, wTth,
                     wTtl, xth, xtl, normpart);
  hipLaunchKernelGGL(gemm_fused, dim3(16, 116), dim3(256), 0, stream, xth, xtl,
                     wTth, wTtl, v, beta, h, M);
  hipLaunchKernelGGL(scan_kernel, dim3(128), dim3(512), 0, stream, h, M,
                     normpart, b, beta, out, wgcnt);
  hipLaunchKernelGGL(finalize_kernel, dim3(1), dim3(128), 0, stream, wgcnt,
                     out);
}